// Round 7
// baseline (96.518 us; speedup 1.0000x reference)
//
#include <hip/hip_runtime.h>
#include <cstdint>
#include <cstddef>

// Problem constants (reference: B=8, S=4096, N_STATE=1024, N_HEAD=16)
#define S_LEN   4096
#define NROT    32
#define NGRP    8192    // groups of 64 rows (64x64 fp32 tile each)

typedef __attribute__((ext_vector_type(8))) short  short8x;  // 8 bf16 (4 VGPR)
typedef __attribute__((ext_vector_type(4))) float  floatx4;  // 4 f32

__device__ __host__ inline unsigned short f2bf(float f) {
  union { float f; unsigned u; } c; c.f = f;
  unsigned u = c.u;
  return (unsigned short)((u + 0x7fffu + ((u >> 16) & 1u)) >> 16);
}
__device__ inline float bf2f(unsigned short h) {
  union { unsigned u; float f; } c; c.u = ((unsigned)h) << 16;
  return c.f;
}

// ---------------------------------------------------------------------------
// Setup: blocks 0..511 fill the interleaved cos/sin table (4096 x 32 float2).
// Block 512: compose M = G0..G31 * R, split into bf16 hi/lo, and emit the
// 16 M-fragments (nt x ks x {hi,lo}) in lane-fragment order:
//   Bfrag[f*64 + lane] = 8 bf16: M[k = ks*32 + (lane>>4)*8 + j][col = nt*16 + (lane&15)]
// (Used as the MFMA *A*-operand in the main kernel: operand-swapped product
//  OUT^T = M^T-frag x X-frag gives lane-contiguous output columns.)
// ---------------------------------------------------------------------------
__global__ void setup_kernel(const float* __restrict__ thetas,
                             const float* __restrict__ theta_scale,
                             const float* __restrict__ r_matrix,
                             const int*   __restrict__ r_pairs,
                             const float* __restrict__ inv_freq,
                             uint4* __restrict__ Bfrag,
                             float2* __restrict__ csT) {
  if (blockIdx.x < 512) {
    int idx = blockIdx.x * 256 + threadIdx.x;   // 0..131071 = s*32 + f
    int s = idx >> 5;
    int f = idx & 31;
    float ang = (float)s * inv_freq[f];
    csT[idx] = make_float2(cosf(ang), sinf(ang));
    return;
  }
  __shared__ float C[64 * 65];                  // rotations applied to identity
  __shared__ float Mm[64 * 64];                 // final M = C * R (row-major)
  int tid = threadIdx.x;
  if (tid < 64) {
    for (int c = 0; c < 64; ++c) C[tid * 65 + c] = (tid == c) ? 1.0f : 0.0f;
    float sc = theta_scale[0];
    for (int q = 0; q < NROT; ++q) {
      float th = thetas[q] * sc;
      float cs = cosf(th), sn = sinf(th);
      int i = r_pairs[2 * q], j = r_pairs[2 * q + 1];
      float xi = C[tid * 65 + i];
      float xj = C[tid * 65 + j];
      C[tid * 65 + i] =  xi * cs + xj * sn;
      C[tid * 65 + j] = -xi * sn + xj * cs;
    }
  }
  __syncthreads();
  for (int o = tid; o < 64 * 64; o += 256) {
    int t = o >> 6, c = o & 63;
    float a = 0.0f;
    for (int k = 0; k < 64; ++k) a = fmaf(C[t * 65 + k], r_matrix[k * 64 + c], a);
    Mm[o] = a;
  }
  __syncthreads();
  // emit 16 fragments x 64 lanes
  for (int e = tid; e < 16 * 64; e += 256) {
    int f = e >> 6, l = e & 63;
    int hl = f & 1, ks = (f >> 1) & 1, nt = f >> 2;
    int col = nt * 16 + (l & 15);
    unsigned short w[8];
    for (int j = 0; j < 8; ++j) {
      int k = ks * 32 + (l >> 4) * 8 + j;
      float m = Mm[k * 64 + col];
      unsigned short h = f2bf(m);
      if (hl == 0) w[j] = h;
      else         w[j] = f2bf(m - bf2f(h));
    }
    uint4 pk;
    pk.x = (unsigned)w[0] | ((unsigned)w[1] << 16);
    pk.y = (unsigned)w[2] | ((unsigned)w[3] << 16);
    pk.z = (unsigned)w[4] | ((unsigned)w[5] << 16);
    pk.w = (unsigned)w[6] | ((unsigned)w[7] << 16);
    Bfrag[e] = pk;
  }
}

// ---------------------------------------------------------------------------
// Main: one wave per 64x64 group (8192 waves, 2048 blocks). OPERAND-SWAPPED
// MFMA: acc = mfma(M-frag, X-frag) = OUT^T fragments, so lane l holds
// OUT[row = l&15][4 consecutive cols nt*16 + (l>>4)*4 + 0..3] = two complete
// RoPE (even,odd) pairs IN-LANE. Epilogue = 1 float4 cos/sin load + 8 VALU +
// 2 float2 stores per nt. NO LDS, NO shuffles, NO barriers anywhere --
// R5's lgkmcnt-serialized LDS transpose epilogue was the latency bottleneck.
// A prefetched one tile ahead; dual 3-deep MFMA chains (split-bf16, ks0/ks1).
// ---------------------------------------------------------------------------
__global__ __launch_bounds__(256)
void rotary_main(const float* __restrict__ x,
                 const uint4* __restrict__ Bfrag,
                 const float2* __restrict__ csT,
                 float* __restrict__ out) {
  const int tid  = threadIdx.x;
  const int lane = tid & 63;
  const int wid  = tid >> 6;
  const int g    = blockIdx.x * 4 + wid;        // group id 0..8191

  // all 16 M fragments resident for the whole wave (A-operand of the MFMA)
  const short8x* Bp = (const short8x*)Bfrag;
  short8x Bf[16];
  #pragma unroll
  for (int f = 0; f < 16; ++f) Bf[f] = Bp[f * 64 + lane];

  const int lr = lane & 15;                     // OUT row-in-tile / X row
  const int lk = lane >> 4;                     // X k-block / OUT col-block
  const int D0 = lk * 2;                        // pair base within nt tile

  const float* xg = x + (size_t)g * 4096;
  float* og = out + (size_t)g * 4096;

  floatx4 a[2][4];
  // X fragments for tile t: x[row = t*16+lr][k], k split ks0 (0..31)/ks1 (32..63)
  #define LOAD_A(t, sl)                                                   \
    { const float* xr = xg + (size_t)((t) * 16 + lr) * 64 + lk * 8;       \
      a[sl][0] = *(const floatx4*)(xr);                                   \
      a[sl][1] = *(const floatx4*)(xr + 4);                                \
      a[sl][2] = *(const floatx4*)(xr + 32);                               \
      a[sl][3] = *(const floatx4*)(xr + 36); }

  LOAD_A(0, 0)

  #pragma unroll
  for (int t = 0; t < 4; ++t) {
    const int cur = t & 1;
    // convert current X to bf16 hi/lo (ks0 -> Xh0/Xl0, ks1 -> Xh1/Xl1)
    short8x Xh0, Xl0, Xh1, Xl1;
    #pragma unroll
    for (int i = 0; i < 8; ++i) {
      float v0 = (i < 4) ? a[cur][0][i] : a[cur][1][i - 4];
      float v1 = (i < 4) ? a[cur][2][i] : a[cur][3][i - 4];
      unsigned short h0 = f2bf(v0);
      unsigned short h1 = f2bf(v1);
      Xh0[i] = (short)h0; Xl0[i] = (short)f2bf(v0 - bf2f(h0));
      Xh1[i] = (short)h1; Xl1[i] = (short)f2bf(v1 - bf2f(h1));
    }
    // prefetch next tile's X under this tile's compute
    if (t < 3) LOAD_A(t + 1, (t + 1) & 1)

    const int spos = (g * 4 + t) & (S_LEN - 1); // wave-uniform seq pos
    const float2* cst = csT + spos * 32;
    // cos/sin for this lane's two pairs in each nt tile: (c0,s0,c1,s1)
    float4 cs[4];
    #pragma unroll
    for (int nt = 0; nt < 4; ++nt)
      cs[nt] = *(const float4*)(cst + nt * 8 + D0);

    float* orow = og + (size_t)(t * 16 + lr) * 64;

    #pragma unroll
    for (int nt = 0; nt < 4; ++nt) {
      floatx4 acc0 = {0.f, 0.f, 0.f, 0.f};
      floatx4 acc1 = {0.f, 0.f, 0.f, 0.f};
      // OUT^T = M-frag x X-frag; 3 split terms per ks, dual chains
      acc0 = __builtin_amdgcn_mfma_f32_16x16x32_bf16(Bf[nt * 4 + 0], Xh0, acc0, 0, 0, 0); // Mh ks0
      acc1 = __builtin_amdgcn_mfma_f32_16x16x32_bf16(Bf[nt * 4 + 2], Xh1, acc1, 0, 0, 0); // Mh ks1
      acc0 = __builtin_amdgcn_mfma_f32_16x16x32_bf16(Bf[nt * 4 + 1], Xh0, acc0, 0, 0, 0); // Ml ks0
      acc1 = __builtin_amdgcn_mfma_f32_16x16x32_bf16(Bf[nt * 4 + 3], Xh1, acc1, 0, 0, 0); // Ml ks1
      acc0 = __builtin_amdgcn_mfma_f32_16x16x32_bf16(Bf[nt * 4 + 0], Xl0, acc0, 0, 0, 0); // Mh ks0 * Xl
      acc1 = __builtin_amdgcn_mfma_f32_16x16x32_bf16(Bf[nt * 4 + 2], Xl1, acc1, 0, 0, 0); // Mh ks1 * Xl

      // lane holds y[row][2D], y[row][2D+1], y[row][2D+2], y[row][2D+3]
      // with D = nt*8 + D0: two complete RoPE pairs, fully in-lane.
      const float a0 = acc0[0] + acc1[0];
      const float b0 = acc0[1] + acc1[1];
      const float a1 = acc0[2] + acc1[2];
      const float b1 = acc0[3] + acc1[3];
      const float c0 = cs[nt].x, s0 = cs[nt].y;
      const float c1 = cs[nt].z, s1 = cs[nt].w;
      float2 ev, od;
      ev.x = fmaf(a0, c0, -(b0 * s0));          // out[D]      = x1*c - x2*s
      ev.y = fmaf(a1, c1, -(b1 * s1));          // out[D+1]
      od.x = fmaf(a0, s0,   b0 * c0);           // out[32+D]   = x1*s + x2*c
      od.y = fmaf(a1, s1,   b1 * c1);           // out[32+D+1]
      *(float2*)(orow + nt * 8 + D0)      = ev;
      *(float2*)(orow + 32 + nt * 8 + D0) = od;
    }
  }
  #undef LOAD_A
}

extern "C" void kernel_launch(void* const* d_in, const int* in_sizes, int n_in,
                              void* d_out, int out_size, void* d_ws, size_t ws_size,
                              hipStream_t stream) {
  const float* x           = (const float*)d_in[0];
  const float* thetas      = (const float*)d_in[1];
  const float* theta_scale = (const float*)d_in[2];
  const float* r_matrix    = (const float*)d_in[3];
  const float* inv_freq    = (const float*)d_in[4];
  const int*   r_pairs     = (const int*)d_in[5];

  uint4*  Bfrag = (uint4*)d_ws;                 // 16*64*16B = 16KB
  float2* csT   = (float2*)((char*)d_ws + 16384);  // 4096*32*8B = 1MB
  float*  outp  = (float*)d_out;

  setup_kernel<<<513, 256, 0, stream>>>(thetas, theta_scale, r_matrix, r_pairs,
                                        inv_freq, Bfrag, csT);
  rotary_main<<<NGRP / 4, 256, 0, stream>>>(x, Bfrag, csT, outp);
}